// Round 12
// baseline (237.758 us; speedup 1.0000x reference)
//
#include <hip/hip_runtime.h>

#define NN 50000
#define NE 1250000
#define DD 64
#define KRF 1563      // fine bins of 32 nodes (dst >> 5); 1563*32 = 50016
#define BSH 5         // log2 nodes per bin
#define SCAPF 1024    // staged-edge capacity per bin (mean 800, +8 sigma)
#define SCSHF 10      // log2(SCAPF)
#define CPAD 4        // counter padding: 1 counter per 16 ints = 64 B line

// ---------------------------------------------------------------------------
// ws layout: rcur[KRF<<CPAD] ints (100KB, 1 counter per 64B line) |
//            Wt[4096] f32 | staging[KRF*SCAPF] u32 (~6.4 MB)
// staging payload = src(16b) | (ef1*8+ef0)(5b)<<16 | (dst&31)(5b)<<21
// R15: ZERO-PHASE k_part. Every prior variant (R5/R8/R9/R10/R12/R13) kept
// the same multi-phase skeleton (LDS init + hist atomics + sync + alloc +
// sync + LDS cur atomics) and all landed at the same ~100us residual; the
// one design never tried is no phases at all: per-edge global atomicAdd on
// a line-padded counter, direct scatter store. No LDS, no __syncthreads.
// Bin order becomes arbitrary — softmax sums are permutation-invariant.
// agg is byte-exact R10 (88.9us proven) reading rcur[bin<<CPAD].
// ---------------------------------------------------------------------------

__global__ __launch_bounds__(256) void k_part(
    const int4* __restrict__ src4, const int4* __restrict__ dst4,
    const int4* __restrict__ ef04, const int4* __restrict__ ef14,
    const float* __restrict__ W, float* __restrict__ Wt,
    int* __restrict__ rcur, unsigned* __restrict__ staging)
{
    const int t  = threadIdx.x;
    const int gb = blockIdx.x;

    if (gb == 0)   // piggyback W transpose
        for (int i = t; i < 4096; i += 256)
            Wt[(i & 63) * DD + (i >> 6)] = W[i];

    const int i4 = gb * 256 + t;
    if (i4 >= NE / 4) return;

    const int4 s  = src4[i4], d = dst4[i4];
    const int4 f0 = ef04[i4], f1 = ef14[i4];
    const int ds[4] = {d.x, d.y, d.z, d.w};
    const int ss[4] = {s.x, s.y, s.z, s.w};
    const int a0[4] = {f0.x, f0.y, f0.z, f0.w};
    const int a1[4] = {f1.x, f1.y, f1.z, f1.w};

#pragma unroll
    for (int u = 0; u < 4; ++u) {
        const int bin = ds[u] >> BSH;
        const unsigned pay = (unsigned)ss[u]
            | ((unsigned)(a1[u] * 8 + a0[u]) << 16)
            | ((unsigned)(ds[u] & 31) << 21);
        const int pos = atomicAdd(&rcur[bin << CPAD], 1);
        if (pos < SCAPF) staging[(bin << SCSHF) + pos] = pay;
    }
}

// ---------------------------------------------------------------------------
// Fused bucket + aggregation + MessageNorm + residual + GEMM.
// Block = 32 nodes = exactly one staging bin. Byte-exact R10 (88.9us).
// ---------------------------------------------------------------------------
__global__ __launch_bounds__(256, 4) void genconv_agg(
    const float* __restrict__ nf,
    const float* __restrict__ emb0, const float* __restrict__ emb1,
    const float* __restrict__ Wt,  const float* __restrict__ b,
    const float* __restrict__ beta_p, const float* __restrict__ scale_p,
    const unsigned* __restrict__ staging, const int* __restrict__ rcur,
    float* __restrict__ out)
{
    __shared__ float emb_s[32 * DD];      // 8 KB
    __shared__ float feat_s[4][DD];       // 1 KB
    __shared__ unsigned buck[32 * DD];    // 8 KB
    __shared__ int ldeg[32];

    const int t    = threadIdx.x;
    const int w    = t >> 6;
    const int lane = t & 63;
    const int bin  = blockIdx.x;
    const int base_node = bin << BSH;

    if (t < 32) ldeg[t] = 0;
    for (int i = t; i < 32 * DD; i += 256) {
        const int rr = i >> 6, c = i & 63;
        emb_s[i] = emb0[(rr & 7) * DD + c] + emb1[(rr >> 3) * DD + c];
    }

    float4 wc[16];
#pragma unroll
    for (int k = 0; k < 16; ++k)
        wc[k] = *(const float4*)(Wt + lane * DD + 4 * k);

    const float bias  = b[lane];
    const float beta  = beta_p[0];
    const float scale = scale_p[0];
    __syncthreads();

    // ---- Phase 1: bucket own segment's edges into per-node LDS lists ----
    const int ne = min(rcur[bin << CPAD], SCAPF);
    const unsigned* sg = staging + (bin << SCSHF);
    for (int i = t; i < ne; i += 256) {
        const unsigned p = sg[i];
        const int dl  = (p >> 21) & 31;
        const int pos = atomicAdd(&ldeg[dl], 1);
        if (pos < DD) buck[(dl << 6) + pos] = p & 0x1FFFFFu;
    }
    __syncthreads();

    // ---- Phase 2: 8 nodes per wave, proven scalar-gather loop ----
    const int nl0 = w << 3;
    unsigned pl = buck[(nl0 << 6) + lane];
    int cn = min(ldeg[nl0], DD);
    int node = base_node + nl0;
    float f = (node < NN) ? nf[(size_t)node * DD + lane] : 0.0f;

    for (int i = 0; i < 8; ++i) {
        const int nl = nl0 + i;
        node = base_node + nl;

        // prefetch next node's state (LDS payload + global feature)
        unsigned pl_n = 0u;
        int cn_n = 0;
        float f_n = 0.0f;
        if (i < 7) {
            pl_n = buck[((nl + 1) << 6) + lane];
            cn_n = ldeg[nl + 1];
            if (node + 1 < NN)
                f_n = nf[(size_t)(node + 1) * DD + lane];
        }

        float num = 0.0f, den = 0.0f;
        for (int j = 0; j < cn; j += 16) {
            float a[16];
            unsigned qv[16];
#pragma unroll
            for (int u = 0; u < 16; ++u) {
                const unsigned qq =
                    (unsigned)__builtin_amdgcn_readlane((int)pl, (j + u) & 63);
                qv[u] = qq;
                const int sidx = min((int)(qq & 0xFFFFu), NN - 1);  // clamp garbage
                a[u] = nf[(size_t)sidx * DD + lane];
            }
#pragma unroll
            for (int u = 0; u < 16; ++u) {
                const float eb = emb_s[(((qv[u] >> 16) & 31) << 6) + lane];
                const float m  = fmaxf(a[u] + eb, 0.0f) + 1e-7f;
                float x = __expf(beta * m);
                x = (j + u < cn) ? x : 0.0f;   // mask tail slots
                den += x;
                num = fmaf(m, x, num);
            }
        }

        const float msg = (den > 0.0f) ? num / den : 0.0f;

        float ss = msg * msg;
        float fs = f * f;
#pragma unroll
        for (int m = 32; m >= 1; m >>= 1) {
            ss += __shfl_xor(ss, m, 64);
            fs += __shfl_xor(fs, m, 64);
        }

        const float feat =
            f + msg * (1.0f / fmaxf(sqrtf(ss), 1e-12f)) * sqrtf(fs) * scale;

        feat_s[w][lane] = feat;

        float acc = bias;
#pragma unroll
        for (int k = 0; k < 16; ++k) {
            const float4 fv = *(const float4*)&feat_s[w][4 * k];
            acc = fmaf(fv.x, wc[k].x, acc);
            acc = fmaf(fv.y, wc[k].y, acc);
            acc = fmaf(fv.z, wc[k].z, acc);
            acc = fmaf(fv.w, wc[k].w, acc);
        }
        if (node < NN)
            out[(size_t)node * DD + lane] = acc;

        pl = pl_n;
        cn = min(cn_n, DD);
        f  = f_n;
    }
}

extern "C" void kernel_launch(void* const* d_in, const int* in_sizes, int n_in,
                              void* d_out, int out_size, void* d_ws, size_t ws_size,
                              hipStream_t stream)
{
    const float* nf    = (const float*)d_in[0];
    const float* emb0  = (const float*)d_in[1];
    const float* emb1  = (const float*)d_in[2];
    const float* W     = (const float*)d_in[3];
    const float* b     = (const float*)d_in[4];
    const float* beta  = (const float*)d_in[5];
    const float* scale = (const float*)d_in[6];
    const int* src = (const int*)d_in[7];
    const int* dst = (const int*)d_in[8];
    const int* ef0 = (const int*)d_in[9];
    const int* ef1 = (const int*)d_in[10];

    int*      rcur    = (int*)d_ws;                       // KRF<<CPAD ints (100KB)
    float*    Wt      = (float*)(rcur + (KRF << CPAD));   // 4096 f32
    unsigned* staging = (unsigned*)(Wt + 4096);           // KRF*SCAPF u32 (~6.4MB)

    hipMemsetAsync(rcur, 0, (size_t)(KRF << CPAD) * sizeof(int), stream);

    k_part<<<(NE / 4 + 255) / 256, 256, 0, stream>>>(
        (const int4*)src, (const int4*)dst, (const int4*)ef0, (const int4*)ef1,
        W, Wt, rcur, staging);

    genconv_agg<<<KRF, 256, 0, stream>>>(
        nf, emb0, emb1, Wt, b, beta, scale, staging, rcur, (float*)d_out);
}

// Round 13
// 207.013 us; speedup vs baseline: 1.1485x; 1.1485x over previous
//
#include <hip/hip_runtime.h>

#define NN 50000
#define NE 1250000
#define DD 64
#define KR 391        // ranges of 128 nodes (dst >> 7)
#define RSH 7         // log2 nodes per range
#define RCAP 6144     // staged slots per range incl. chunk padding (mean ~5100)
#define SENT 0xFFFFFFFFu

// ---------------------------------------------------------------------------
// ws layout: rcur[512] ints | Wt[4096] f32 | staging[KR*RCAP] u32 (9.6 MB)
// staging payload = src(16b) | (ef1*8+ef0)(5b)<<16 | (dst&127)(7b)<<21
// R16: FULL-LINE staging writes. Residual ranking across 7 partition
// variants tracks partial-line density of the scattered staging stores
// (dense runs best, interleaved atomics worst); bottom-up models say all
// variants should cost 10-25us yet all measure ~100+: the unmodeled cost is
// the end-of-kernel writeback RMW of ~1.25M partially-dirty 64B lines
// (~160MB hidden HBM traffic, charged between dispatches). Fix: allocate
// per-(block,bin) chunks of 16 u32 = one aligned 64B line, pad with
// sentinels -> every staging line fully written -> clean writeback.
// k_part/agg otherwise byte-follow R8 (best measured residual, 101us).
// ---------------------------------------------------------------------------

__global__ __launch_bounds__(512) void k_part(
    const int4* __restrict__ src4, const int4* __restrict__ dst4,
    const int4* __restrict__ ef04, const int4* __restrict__ ef14,
    const float* __restrict__ W, float* __restrict__ Wt,
    int* __restrict__ rcur, unsigned* __restrict__ staging)
{
    __shared__ int hist[KR], rbase[KR], cur[KR];
    const int t  = threadIdx.x;
    const int gb = blockIdx.x;

    for (int i = t; i < KR; i += 512) { hist[i] = 0; cur[i] = 0; }
    if (gb == 0)   // piggyback W transpose
        for (int i = t; i < 4096; i += 512)
            Wt[(i & 63) * DD + (i >> 6)] = W[i];
    __syncthreads();

    unsigned pay[8];
    int rr[8];
#pragma unroll
    for (int u = 0; u < 8; ++u) rr[u] = -1;

#pragma unroll
    for (int g = 0; g < 2; ++g) {
        const int i4 = gb * 1024 + t + g * 512;
        if (i4 < NE / 4) {
            const int4 s  = src4[i4], d = dst4[i4];
            const int4 f0 = ef04[i4], f1 = ef14[i4];
            const int ds[4] = {d.x, d.y, d.z, d.w};
            const int ss[4] = {s.x, s.y, s.z, s.w};
            const int a0[4] = {f0.x, f0.y, f0.z, f0.w};
            const int a1[4] = {f1.x, f1.y, f1.z, f1.w};
#pragma unroll
            for (int u = 0; u < 4; ++u) {
                const int k = g * 4 + u;
                rr[k]  = ds[u] >> RSH;
                pay[k] = (unsigned)ss[u] | ((unsigned)(a1[u] * 8 + a0[u]) << 16)
                         | ((unsigned)(ds[u] & 127) << 21);
            }
        }
    }
#pragma unroll
    for (int u = 0; u < 8; ++u)
        if (rr[u] >= 0) atomicAdd(&hist[rr[u]], 1);
    __syncthreads();

    // chunked allocation: whole 16-slot (64B) lines per (block,bin)
    for (int i = t; i < KR; i += 512) {
        const int h = hist[i];
        if (h) rbase[i] = atomicAdd(&rcur[i], (h + 15) & ~15);
    }
    __syncthreads();

#pragma unroll
    for (int u = 0; u < 8; ++u) {
        if (rr[u] >= 0) {
            const int r    = rr[u];
            const int pos  = rbase[r] + atomicAdd(&cur[r], 1);
            if (pos < RCAP) staging[(size_t)r * RCAP + pos] = pay[u];
        }
    }
    __syncthreads();

    // pad the remainder of each owned chunk -> lines fully dirty, no RMW
    for (int i = t; i < KR; i += 512) {
        const int h = hist[i];
        if (h) {
            const int rb = rbase[i];
            const int hi = (h + 15) & ~15;
            for (int p = h; p < hi; ++p) {
                const int pos = rb + p;
                if (pos < RCAP) staging[(size_t)i * RCAP + pos] = SENT;
            }
        }
    }
}

// ---------------------------------------------------------------------------
// Fused bucket + aggregation + MessageNorm + residual + GEMM.
// Block = one quarter-range (32 nodes); x4 filter scan of the range's
// staging (R8 structure, 96us proven) + sentinel skip.
// ---------------------------------------------------------------------------
__global__ __launch_bounds__(256, 4) void genconv_agg(
    const float* __restrict__ nf,
    const float* __restrict__ emb0, const float* __restrict__ emb1,
    const float* __restrict__ Wt,  const float* __restrict__ b,
    const float* __restrict__ beta_p, const float* __restrict__ scale_p,
    const unsigned* __restrict__ staging, const int* __restrict__ rcur,
    float* __restrict__ out)
{
    __shared__ float emb_s[32 * DD];      // 8 KB
    __shared__ float feat_s[4][DD];       // 1 KB
    __shared__ unsigned buck[32 * DD];    // 8 KB
    __shared__ int ldeg[32];

    const int t    = threadIdx.x;
    const int w    = t >> 6;
    const int lane = t & 63;
    const int r    = blockIdx.x >> 2;     // range
    const int q    = blockIdx.x & 3;      // quarter within range
    const int base_node = (r << RSH) + (q << 5);

    if (t < 32) ldeg[t] = 0;
    for (int i = t; i < 32 * DD; i += 256) {
        const int rr = i >> 6, c = i & 63;
        emb_s[i] = emb0[(rr & 7) * DD + c] + emb1[(rr >> 3) * DD + c];
    }

    float4 wc[16];
#pragma unroll
    for (int k = 0; k < 16; ++k)
        wc[k] = *(const float4*)(Wt + lane * DD + 4 * k);

    const float bias  = b[lane];
    const float beta  = beta_p[0];
    const float scale = scale_p[0];
    __syncthreads();

    // ---- Phase 1: filter this quarter's edges out of the range staging ----
    const int ne = min(rcur[r], RCAP);
    const unsigned* sg = staging + (size_t)r * RCAP;
    for (int i = t; i < ne; i += 256) {
        const unsigned p = sg[i];
        if (p != SENT) {
            const int d = (p >> 21) & 127;
            if ((d >> 5) == q) {
                const int dl  = d & 31;
                const int pos = atomicAdd(&ldeg[dl], 1);
                if (pos < DD) buck[(dl << 6) + pos] = p & 0x1FFFFFu;
            }
        }
    }
    __syncthreads();

    // ---- Phase 2: 8 nodes per wave, proven scalar-gather loop ----
    const int nl0 = w << 3;
    unsigned pl = buck[(nl0 << 6) + lane];
    int cn = min(ldeg[nl0], DD);
    int node = base_node + nl0;
    float f = (node < NN) ? nf[(size_t)node * DD + lane] : 0.0f;

    for (int i = 0; i < 8; ++i) {
        const int nl = nl0 + i;
        node = base_node + nl;

        // prefetch next node's state (LDS payload + global feature)
        unsigned pl_n = 0u;
        int cn_n = 0;
        float f_n = 0.0f;
        if (i < 7) {
            pl_n = buck[((nl + 1) << 6) + lane];
            cn_n = ldeg[nl + 1];
            if (node + 1 < NN)
                f_n = nf[(size_t)(node + 1) * DD + lane];
        }

        float num = 0.0f, den = 0.0f;
        for (int j = 0; j < cn; j += 16) {
            float a[16];
            unsigned qv[16];
#pragma unroll
            for (int u = 0; u < 16; ++u) {
                const unsigned qq =
                    (unsigned)__builtin_amdgcn_readlane((int)pl, (j + u) & 63);
                qv[u] = qq;
                const int sidx = min((int)(qq & 0xFFFFu), NN - 1);  // clamp garbage
                a[u] = nf[(size_t)sidx * DD + lane];
            }
#pragma unroll
            for (int u = 0; u < 16; ++u) {
                const float eb = emb_s[(((qv[u] >> 16) & 31) << 6) + lane];
                const float m  = fmaxf(a[u] + eb, 0.0f) + 1e-7f;
                float x = __expf(beta * m);
                x = (j + u < cn) ? x : 0.0f;   // mask tail slots
                den += x;
                num = fmaf(m, x, num);
            }
        }

        const float msg = (den > 0.0f) ? num / den : 0.0f;

        float ss = msg * msg;
        float fs = f * f;
#pragma unroll
        for (int m = 32; m >= 1; m >>= 1) {
            ss += __shfl_xor(ss, m, 64);
            fs += __shfl_xor(fs, m, 64);
        }

        const float feat =
            f + msg * (1.0f / fmaxf(sqrtf(ss), 1e-12f)) * sqrtf(fs) * scale;

        feat_s[w][lane] = feat;

        float acc = bias;
#pragma unroll
        for (int k = 0; k < 16; ++k) {
            const float4 fv = *(const float4*)&feat_s[w][4 * k];
            acc = fmaf(fv.x, wc[k].x, acc);
            acc = fmaf(fv.y, wc[k].y, acc);
            acc = fmaf(fv.z, wc[k].z, acc);
            acc = fmaf(fv.w, wc[k].w, acc);
        }
        if (node < NN)
            out[(size_t)node * DD + lane] = acc;

        pl = pl_n;
        cn = min(cn_n, DD);
        f  = f_n;
    }
}

extern "C" void kernel_launch(void* const* d_in, const int* in_sizes, int n_in,
                              void* d_out, int out_size, void* d_ws, size_t ws_size,
                              hipStream_t stream)
{
    const float* nf    = (const float*)d_in[0];
    const float* emb0  = (const float*)d_in[1];
    const float* emb1  = (const float*)d_in[2];
    const float* W     = (const float*)d_in[3];
    const float* b     = (const float*)d_in[4];
    const float* beta  = (const float*)d_in[5];
    const float* scale = (const float*)d_in[6];
    const int* src = (const int*)d_in[7];
    const int* dst = (const int*)d_in[8];
    const int* ef0 = (const int*)d_in[9];
    const int* ef1 = (const int*)d_in[10];

    int*      rcur    = (int*)d_ws;                 // 512 ints
    float*    Wt      = (float*)(rcur + 512);       // 4096 f32
    unsigned* staging = (unsigned*)(Wt + 4096);     // KR*RCAP u32 (~9.6 MB)

    hipMemsetAsync(rcur, 0, 512 * sizeof(int), stream);

    k_part<<<(NE / 4 + 1023) / 1024, 512, 0, stream>>>(
        (const int4*)src, (const int4*)dst, (const int4*)ef0, (const int4*)ef1,
        W, Wt, rcur, staging);

    genconv_agg<<<KR * 4, 256, 0, stream>>>(
        nf, emb0, emb1, Wt, b, beta, scale, staging, rcur, (float*)d_out);
}